// Round 1
// baseline (325.003 us; speedup 1.0000x reference)
//
#include <hip/hip_runtime.h>
#include <stdint.h>

// ---------------------------------------------------------------------------
// MultiHeadSelfAttention: B=8, N=1024, D=1024, H=16, hd=64, scale=0.125
// Pipeline: [x->bf16, wT->bf16] -> GEMM1(qkv + bias, scatter Q/K/Vt bf16)
//           -> flash attention (bf16 MFMA, fp32 online softmax)
//           -> GEMM2(proj + bias, fp32 out)
// Workspace layout (72 MB total):
//   xb      bf16 [8192][1024]   16 MB   (reused as attn_out after GEMM1)
//   wqkvT   bf16 [3072][1024]    6 MB
//   wprojT  bf16 [1024][1024]    2 MB
//   Qb      bf16 [128][1024][64] 16 MB  ([B*H][n][d])
//   Kb      bf16 [128][1024][64] 16 MB
//   Vt      bf16 [128][64][1024] 16 MB  (V transposed: [B*H][d][n])
// ---------------------------------------------------------------------------

typedef short bf16x8 __attribute__((ext_vector_type(8)));
typedef float f32x4 __attribute__((ext_vector_type(4)));

__device__ __forceinline__ short f32_bf16(float f) {
  uint32_t u = __builtin_bit_cast(uint32_t, f);
  u += 0x7FFFu + ((u >> 16) & 1u);   // round-to-nearest-even (no NaN inputs)
  return (short)(u >> 16);
}

__device__ __forceinline__ float bf16_f32(short s) {
  uint32_t u = ((uint32_t)(uint16_t)s) << 16;
  return __builtin_bit_cast(float, u);
}

__device__ __forceinline__ void gload_lds16(const void* g, void* l) {
  __builtin_amdgcn_global_load_lds(
      (const __attribute__((address_space(1))) uint32_t*)g,
      (__attribute__((address_space(3))) uint32_t*)l, 16, 0, 0);
}

// ---------------------------------------------------------------- prep ------
__global__ __launch_bounds__(256) void convert_x_kernel(
    const float* __restrict__ x, short* __restrict__ xb) {
  int i = blockIdx.x * 256 + threadIdx.x;   // one short8 (8 elems) per thread
  const float4 f0 = ((const float4*)x)[i * 2];
  const float4 f1 = ((const float4*)x)[i * 2 + 1];
  bf16x8 o;
  o[0] = f32_bf16(f0.x); o[1] = f32_bf16(f0.y);
  o[2] = f32_bf16(f0.z); o[3] = f32_bf16(f0.w);
  o[4] = f32_bf16(f1.x); o[5] = f32_bf16(f1.y);
  o[6] = f32_bf16(f1.z); o[7] = f32_bf16(f1.w);
  ((bf16x8*)xb)[i] = o;
}

// w: fp32 [1024][N] -> wt: bf16 [N][1024]
__global__ __launch_bounds__(256) void transpose_w_kernel(
    const float* __restrict__ w, short* __restrict__ wt, int N) {
  __shared__ float tile[64][65];
  const int n0 = blockIdx.x * 64, k0 = blockIdx.y * 64;
  const int tr = threadIdx.x >> 6, tc = threadIdx.x & 63;
#pragma unroll
  for (int i = 0; i < 16; ++i) {
    int k = tr + i * 4;
    tile[k][tc] = w[(size_t)(k0 + k) * N + n0 + tc];
  }
  __syncthreads();
#pragma unroll
  for (int i = 0; i < 16; ++i) {
    int a = tr + i * 4;
    wt[(size_t)(n0 + a) * 1024 + k0 + tc] = f32_bf16(tile[tc][a]);
  }
}

// --------------------------------------------------------------- GEMM1 -----
// A: xb bf16 [8192][1024], Bt: wqkvT bf16 [3072][1024].
// 128x128 tile, BK=64, 4 waves (2x2 of 64x64), mfma 16x16x32.
__global__ __launch_bounds__(256, 2) void gemm_qkv_kernel(
    const short* __restrict__ A, const short* __restrict__ Bt,
    const float* __restrict__ bias, short* __restrict__ Qb,
    short* __restrict__ Kb, short* __restrict__ Vt) {
  __shared__ short Asm[128 * 64];
  __shared__ short Bsm[128 * 64];
  const int tid = threadIdx.x;
  const int lane = tid & 63;
  const int w = tid >> 6;
  const int wr = w >> 1, wc = w & 1;
  const int c = lane & 15, g = lane >> 4;

  const int NT = 24;  // 3072/128
  const int tm = blockIdx.x / NT, tn = blockIdx.x % NT;
  const int m0 = tm * 128, n0 = tn * 128;

  f32x4 acc[4][4] = {};

  for (int k0 = 0; k0 < 1024; k0 += 64) {
#pragma unroll
    for (int i = 0; i < 4; ++i) {
      int ch = (w * 4 + i) * 64 + lane;   // 1024 chunks of 16B per matrix
      int r = ch >> 3, c8 = ch & 7;
      gload_lds16(A + (size_t)(m0 + r) * 1024 + k0 + c8 * 8, &Asm[ch * 8]);
      gload_lds16(Bt + (size_t)(n0 + r) * 1024 + k0 + c8 * 8, &Bsm[ch * 8]);
    }
    asm volatile("s_waitcnt vmcnt(0)" ::: "memory");
    __syncthreads();
#pragma unroll
    for (int kk = 0; kk < 2; ++kk) {
      bf16x8 a[4], b[4];
#pragma unroll
      for (int m = 0; m < 4; ++m)
        a[m] = *(const bf16x8*)&Asm[(wr * 64 + m * 16 + c) * 64 + kk * 32 + 8 * g];
#pragma unroll
      for (int n = 0; n < 4; ++n)
        b[n] = *(const bf16x8*)&Bsm[(wc * 64 + n * 16 + c) * 64 + kk * 32 + 8 * g];
#pragma unroll
      for (int m = 0; m < 4; ++m)
#pragma unroll
        for (int n = 0; n < 4; ++n)
          acc[m][n] = __builtin_amdgcn_mfma_f32_16x16x32_bf16(a[m], b[n], acc[m][n], 0, 0, 0);
    }
    __syncthreads();
  }

  // epilogue: +bias, scatter to Q/K/Vt (bf16)
#pragma unroll
  for (int m = 0; m < 4; ++m) {
    const int i_base = m0 + wr * 64 + m * 16 + 4 * g;
#pragma unroll
    for (int n = 0; n < 4; ++n) {
      const int j = n0 + wc * 64 + n * 16 + c;
      const float bj = bias[j];
      const int three = j >> 10, rem = j & 1023, h = rem >> 6, d = rem & 63;
#pragma unroll
      for (int r = 0; r < 4; ++r) {
        const int i = i_base + r;
        const int bb = i >> 10, nn = i & 1023;
        const int bh = bb * 16 + h;
        const short bv = f32_bf16(acc[m][n][r] + bj);
        if (three == 0)
          Qb[(size_t)(bh * 1024 + nn) * 64 + d] = bv;
        else if (three == 1)
          Kb[(size_t)(bh * 1024 + nn) * 64 + d] = bv;
        else
          Vt[(size_t)(bh * 64 + d) * 1024 + nn] = bv;
      }
    }
  }
}

// ----------------------------------------------------------- attention -----
// One block = 128 q-rows of one (b,h). 4 waves x 32 rows. KV tile = 64 keys.
// K/V staged in fragment-linear LDS (lane-indexed 16B chunks, conflict-free).
__global__ __launch_bounds__(256, 2) void attn_kernel(
    const short* __restrict__ Qb, const short* __restrict__ Kb,
    const short* __restrict__ Vt, short* __restrict__ Ao) {
  __shared__ short Kf[8 * 64 * 8];    // [kt*2+ks][lane][8]
  __shared__ short Vf[8 * 64 * 8];    // [dt*2+kk][lane][8]
  __shared__ short Pl[4][16 * 72];    // per-wave P bounce, pitch 72 (16B-aligned rows)

  const int tid = threadIdx.x, lane = tid & 63, w = tid >> 6;
  const int c = lane & 15, g = lane >> 4;
  const int bh = blockIdx.x >> 3, qb = blockIdx.x & 7;
  const int bb = bh >> 4, h = bh & 15;
  const int q0 = qb * 128 + w * 32;

  // Q fragments: 2 m-sets x 2 k-steps
  bf16x8 qf[2][2];
#pragma unroll
  for (int m = 0; m < 2; ++m)
#pragma unroll
    for (int ks = 0; ks < 2; ++ks)
      qf[m][ks] = *(const bf16x8*)(Qb + (size_t)(bh * 1024 + q0 + m * 16 + c) * 64 + ks * 32 + 8 * g);

  f32x4 o[2][4] = {};
  float mrun[2][4], lrun[2][4];
#pragma unroll
  for (int m = 0; m < 2; ++m)
#pragma unroll
    for (int r = 0; r < 4; ++r) { mrun[m][r] = -1e30f; lrun[m][r] = 0.f; }

  const int row_r = tid >> 2;  // 0..63: K row (key) / Vt row (d)
  const int seg = tid & 3;

  for (int t = 0; t < 16; ++t) {
    const int kv0 = t * 64;
    // ---- stage K tile into fragment layout
    {
      const short* src = Kb + (size_t)(bh * 1024 + kv0 + row_r) * 64 + seg * 16;
      bf16x8 v0 = *(const bf16x8*)(src);
      bf16x8 v1 = *(const bf16x8*)(src + 8);
      const int kt = row_r >> 4;
#pragma unroll
      for (int hh = 0; hh < 2; ++hh) {
        const int d0 = seg * 16 + hh * 8;
        const int ks = d0 >> 5;
        const int slot = (row_r & 15) + 16 * ((d0 & 31) >> 3);
        *(bf16x8*)&Kf[((kt * 2 + ks) * 64 + slot) * 8] = hh ? v1 : v0;
      }
      // ---- stage V tile (already transposed in global)
      const short* vsrc = Vt + (size_t)(bh * 64 + row_r) * 1024 + kv0 + seg * 16;
      bf16x8 u0 = *(const bf16x8*)(vsrc);
      bf16x8 u1 = *(const bf16x8*)(vsrc + 8);
      const int dt = row_r >> 4;
#pragma unroll
      for (int hh = 0; hh < 2; ++hh) {
        const int k0l = seg * 16 + hh * 8;
        const int kk = k0l >> 5;
        const int slot = (row_r & 15) + 16 * ((k0l & 31) >> 3);
        *(bf16x8*)&Vf[((dt * 2 + kk) * 64 + slot) * 8] = hh ? u1 : u0;
      }
    }
    __syncthreads();

#pragma unroll
    for (int m = 0; m < 2; ++m) {
      // ---- QK^T: S[q=4g+r][key=kt*16+c]
      f32x4 s[4];
#pragma unroll
      for (int kt = 0; kt < 4; ++kt) {
        f32x4 sa = {};
#pragma unroll
        for (int ks = 0; ks < 2; ++ks) {
          bf16x8 kb = *(const bf16x8*)&Kf[((kt * 2 + ks) * 64 + lane) * 8];
          sa = __builtin_amdgcn_mfma_f32_16x16x32_bf16(qf[m][ks], kb, sa, 0, 0, 0);
        }
        s[kt] = sa;
      }
      // scale
#pragma unroll
      for (int kt = 0; kt < 4; ++kt)
#pragma unroll
        for (int r = 0; r < 4; ++r) s[kt][r] *= 0.125f;

      // ---- online softmax (rows 4g+r; reduce over the 16 col-lanes)
      float tmax[4], alpha[4], rsum[4];
#pragma unroll
      for (int r = 0; r < 4; ++r) {
        float v = fmaxf(fmaxf(s[0][r], s[1][r]), fmaxf(s[2][r], s[3][r]));
#pragma unroll
        for (int msk = 1; msk < 16; msk <<= 1) v = fmaxf(v, __shfl_xor(v, msk));
        float mnew = fmaxf(mrun[m][r], v);
        alpha[r] = __expf(mrun[m][r] - mnew);
        mrun[m][r] = mnew;
        rsum[r] = 0.f;
      }
#pragma unroll
      for (int dt = 0; dt < 4; ++dt)
#pragma unroll
        for (int r = 0; r < 4; ++r) o[m][dt][r] *= alpha[r];

#pragma unroll
      for (int kt = 0; kt < 4; ++kt)
#pragma unroll
        for (int r = 0; r < 4; ++r) {
          float p = __expf(s[kt][r] - mrun[m][r]);
          rsum[r] += p;
          Pl[w][(4 * g + r) * 72 + kt * 16 + c] = f32_bf16(p);
        }
#pragma unroll
      for (int r = 0; r < 4; ++r) {
        float v = rsum[r];
#pragma unroll
        for (int msk = 1; msk < 16; msk <<= 1) v += __shfl_xor(v, msk);
        lrun[m][r] = lrun[m][r] * alpha[r] + v;
      }

      // ---- PV: O[q=4g+r][d=dt*16+c] += P * V
#pragma unroll
      for (int kk = 0; kk < 2; ++kk) {
        bf16x8 pa = *(const bf16x8*)&Pl[w][c * 72 + kk * 32 + 8 * g];
#pragma unroll
        for (int dt = 0; dt < 4; ++dt) {
          bf16x8 vb = *(const bf16x8*)&Vf[((dt * 2 + kk) * 64 + lane) * 8];
          o[m][dt] = __builtin_amdgcn_mfma_f32_16x16x32_bf16(pa, vb, o[m][dt], 0, 0, 0);
        }
      }
    }
    __syncthreads();
  }

  // ---- write attn_out bf16 [b][n][h*64+d]
#pragma unroll
  for (int m = 0; m < 2; ++m)
#pragma unroll
    for (int dt = 0; dt < 4; ++dt)
#pragma unroll
      for (int r = 0; r < 4; ++r) {
        const int n = q0 + m * 16 + 4 * g + r;
        const float v = o[m][dt][r] / lrun[m][r];
        Ao[(size_t)(bb * 1024 + n) * 1024 + h * 64 + dt * 16 + c] = f32_bf16(v);
      }
}

// --------------------------------------------------------------- GEMM2 -----
__global__ __launch_bounds__(256, 2) void gemm_proj_kernel(
    const short* __restrict__ A, const short* __restrict__ Bt,
    const float* __restrict__ bias, float* __restrict__ out) {
  __shared__ short Asm[128 * 64];
  __shared__ short Bsm[128 * 64];
  const int tid = threadIdx.x;
  const int lane = tid & 63;
  const int w = tid >> 6;
  const int wr = w >> 1, wc = w & 1;
  const int c = lane & 15, g = lane >> 4;

  const int NT = 8;  // 1024/128
  const int tm = blockIdx.x / NT, tn = blockIdx.x % NT;
  const int m0 = tm * 128, n0 = tn * 128;

  f32x4 acc[4][4] = {};

  for (int k0 = 0; k0 < 1024; k0 += 64) {
#pragma unroll
    for (int i = 0; i < 4; ++i) {
      int ch = (w * 4 + i) * 64 + lane;
      int r = ch >> 3, c8 = ch & 7;
      gload_lds16(A + (size_t)(m0 + r) * 1024 + k0 + c8 * 8, &Asm[ch * 8]);
      gload_lds16(Bt + (size_t)(n0 + r) * 1024 + k0 + c8 * 8, &Bsm[ch * 8]);
    }
    asm volatile("s_waitcnt vmcnt(0)" ::: "memory");
    __syncthreads();
#pragma unroll
    for (int kk = 0; kk < 2; ++kk) {
      bf16x8 a[4], b[4];
#pragma unroll
      for (int m = 0; m < 4; ++m)
        a[m] = *(const bf16x8*)&Asm[(wr * 64 + m * 16 + c) * 64 + kk * 32 + 8 * g];
#pragma unroll
      for (int n = 0; n < 4; ++n)
        b[n] = *(const bf16x8*)&Bsm[(wc * 64 + n * 16 + c) * 64 + kk * 32 + 8 * g];
#pragma unroll
      for (int m = 0; m < 4; ++m)
#pragma unroll
        for (int n = 0; n < 4; ++n)
          acc[m][n] = __builtin_amdgcn_mfma_f32_16x16x32_bf16(a[m], b[n], acc[m][n], 0, 0, 0);
    }
    __syncthreads();
  }

#pragma unroll
  for (int m = 0; m < 4; ++m) {
    const int i_base = m0 + wr * 64 + m * 16 + 4 * g;
#pragma unroll
    for (int n = 0; n < 4; ++n) {
      const int j = n0 + wc * 64 + n * 16 + c;
      const float bj = bias[j];
#pragma unroll
      for (int r = 0; r < 4; ++r)
        out[(size_t)(i_base + r) * 1024 + j] = acc[m][n][r] + bj;
    }
  }
}

// ------------------------------------------------------------- launch ------
extern "C" void kernel_launch(void* const* d_in, const int* in_sizes, int n_in,
                              void* d_out, int out_size, void* d_ws, size_t ws_size,
                              hipStream_t stream) {
  const float* x = (const float*)d_in[0];
  const float* w_qkv = (const float*)d_in[1];
  const float* b_qkv = (const float*)d_in[2];
  const float* w_proj = (const float*)d_in[3];
  const float* b_proj = (const float*)d_in[4];
  float* out = (float*)d_out;

  char* ws = (char*)d_ws;
  const size_t XB_OFF = 0;                       // 16 MB (reused as attn_out)
  const size_t WQKVT_OFF = 16777216;             // 6 MB
  const size_t WPROJT_OFF = WQKVT_OFF + 6291456; // 2 MB
  const size_t Q_OFF = WPROJT_OFF + 2097152;     // 16 MB
  const size_t K_OFF = Q_OFF + 16777216;         // 16 MB
  const size_t VT_OFF = K_OFF + 16777216;        // 16 MB
  short* xb = (short*)(ws + XB_OFF);
  short* wqkvT = (short*)(ws + WQKVT_OFF);
  short* wprojT = (short*)(ws + WPROJT_OFF);
  short* Qb = (short*)(ws + Q_OFF);
  short* Kb = (short*)(ws + K_OFF);
  short* Vt = (short*)(ws + VT_OFF);
  short* attn_o = xb;  // xb dead after GEMM1

  convert_x_kernel<<<dim3(4096), dim3(256), 0, stream>>>(x, xb);
  transpose_w_kernel<<<dim3(48, 16), dim3(256), 0, stream>>>(w_qkv, wqkvT, 3072);
  transpose_w_kernel<<<dim3(16, 16), dim3(256), 0, stream>>>(w_proj, wprojT, 1024);
  gemm_qkv_kernel<<<dim3(64 * 24), dim3(256), 0, stream>>>(xb, wqkvT, b_qkv, Qb, Kb, Vt);
  attn_kernel<<<dim3(1024), dim3(256), 0, stream>>>(Qb, Kb, Vt, attn_o);
  gemm_proj_kernel<<<dim3(64 * 8), dim3(256), 0, stream>>>(attn_o, wprojT, b_proj, out);
}

// Round 2
// 273.864 us; speedup vs baseline: 1.1867x; 1.1867x over previous
//
#include <hip/hip_runtime.h>
#include <stdint.h>

// ---------------------------------------------------------------------------
// MultiHeadSelfAttention: B=8, N=1024, D=1024, H=16, hd=64, scale=0.125
// Pipeline: [x->bf16, wT->bf16] -> GEMM1(qkv + bias, scatter Q/K(pre-scaled)/Vt)
//           -> flash attention (swapped QK^T, in-lane softmax, exp2 units)
//           -> GEMM2(proj + bias, fp32 out)
// K is pre-scaled by 0.125*log2(e) so attention works in exp2 units.
// ---------------------------------------------------------------------------

typedef short bf16x8 __attribute__((ext_vector_type(8)));
typedef float f32x4 __attribute__((ext_vector_type(4)));
typedef uint32_t u32x2 __attribute__((ext_vector_type(2)));

__device__ __forceinline__ short f32_bf16(float f) {
  uint32_t u = __builtin_bit_cast(uint32_t, f);
  u += 0x7FFFu + ((u >> 16) & 1u);   // round-to-nearest-even (no NaN inputs)
  return (short)(u >> 16);
}

__device__ __forceinline__ float exp2_fast(float x) {
  float r; asm("v_exp_f32 %0, %1" : "=v"(r) : "v"(x)); return r;
}

__device__ __forceinline__ uint32_t cvt_pk_bf16(float lo, float hi) {
  uint32_t r;
  asm("v_cvt_pk_bf16_f32 %0, %1, %2" : "=v"(r) : "v"(lo), "v"(hi));
  return r;
}

__device__ __forceinline__ void gload_lds16(const void* g, void* l) {
  __builtin_amdgcn_global_load_lds(
      (const __attribute__((address_space(1))) uint32_t*)g,
      (__attribute__((address_space(3))) uint32_t*)l, 16, 0, 0);
}

// ---------------------------------------------------------------- prep ------
__global__ __launch_bounds__(256) void convert_x_kernel(
    const float* __restrict__ x, short* __restrict__ xb) {
  int i = blockIdx.x * 256 + threadIdx.x;
  const float4 f0 = ((const float4*)x)[i * 2];
  const float4 f1 = ((const float4*)x)[i * 2 + 1];
  bf16x8 o;
  o[0] = f32_bf16(f0.x); o[1] = f32_bf16(f0.y);
  o[2] = f32_bf16(f0.z); o[3] = f32_bf16(f0.w);
  o[4] = f32_bf16(f1.x); o[5] = f32_bf16(f1.y);
  o[6] = f32_bf16(f1.z); o[7] = f32_bf16(f1.w);
  ((bf16x8*)xb)[i] = o;
}

// w: fp32 [1024][N] -> wt: bf16 [N][1024]
__global__ __launch_bounds__(256) void transpose_w_kernel(
    const float* __restrict__ w, short* __restrict__ wt, int N) {
  __shared__ float tile[64][65];
  const int n0 = blockIdx.x * 64, k0 = blockIdx.y * 64;
  const int tr = threadIdx.x >> 6, tc = threadIdx.x & 63;
#pragma unroll
  for (int i = 0; i < 16; ++i) {
    int k = tr + i * 4;
    tile[k][tc] = w[(size_t)(k0 + k) * N + n0 + tc];
  }
  __syncthreads();
#pragma unroll
  for (int i = 0; i < 16; ++i) {
    int a = tr + i * 4;
    wt[(size_t)(n0 + a) * 1024 + k0 + tc] = f32_bf16(tile[tc][a]);
  }
}

// --------------------------------------------------------------- GEMM1 -----
__global__ __launch_bounds__(256, 2) void gemm_qkv_kernel(
    const short* __restrict__ A, const short* __restrict__ Bt,
    const float* __restrict__ bias, short* __restrict__ Qb,
    short* __restrict__ Kb, short* __restrict__ Vt) {
  __shared__ short Asm[128 * 64];
  __shared__ short Bsm[128 * 64];
  const int tid = threadIdx.x;
  const int lane = tid & 63;
  const int w = tid >> 6;
  const int wr = w >> 1, wc = w & 1;
  const int c = lane & 15, g = lane >> 4;

  const int NT = 24;  // 3072/128
  const int tm = blockIdx.x / NT, tn = blockIdx.x % NT;
  const int m0 = tm * 128, n0 = tn * 128;

  f32x4 acc[4][4] = {};

  for (int k0 = 0; k0 < 1024; k0 += 64) {
#pragma unroll
    for (int i = 0; i < 4; ++i) {
      int ch = (w * 4 + i) * 64 + lane;
      int r = ch >> 3, c8 = ch & 7;
      gload_lds16(A + (size_t)(m0 + r) * 1024 + k0 + c8 * 8, &Asm[ch * 8]);
      gload_lds16(Bt + (size_t)(n0 + r) * 1024 + k0 + c8 * 8, &Bsm[ch * 8]);
    }
    asm volatile("s_waitcnt vmcnt(0)" ::: "memory");
    __syncthreads();
#pragma unroll
    for (int kk = 0; kk < 2; ++kk) {
      bf16x8 a[4], b[4];
#pragma unroll
      for (int m = 0; m < 4; ++m)
        a[m] = *(const bf16x8*)&Asm[(wr * 64 + m * 16 + c) * 64 + kk * 32 + 8 * g];
#pragma unroll
      for (int n = 0; n < 4; ++n)
        b[n] = *(const bf16x8*)&Bsm[(wc * 64 + n * 16 + c) * 64 + kk * 32 + 8 * g];
#pragma unroll
      for (int m = 0; m < 4; ++m)
#pragma unroll
        for (int n = 0; n < 4; ++n)
          acc[m][n] = __builtin_amdgcn_mfma_f32_16x16x32_bf16(a[m], b[n], acc[m][n], 0, 0, 0);
    }
    __syncthreads();
  }

  // epilogue: +bias, scatter to Q/K/Vt (bf16); K pre-scaled by 0.125*log2(e)
#pragma unroll
  for (int m = 0; m < 4; ++m) {
    const int i_base = m0 + wr * 64 + m * 16 + 4 * g;
#pragma unroll
    for (int n = 0; n < 4; ++n) {
      const int j = n0 + wc * 64 + n * 16 + c;
      const float bj = bias[j];
      const int three = j >> 10, rem = j & 1023, h = rem >> 6, d = rem & 63;
      const float sc = (three == 1) ? 0.18033688f : 1.0f;
#pragma unroll
      for (int r = 0; r < 4; ++r) {
        const int i = i_base + r;
        const int bb = i >> 10, nn = i & 1023;
        const int bh = bb * 16 + h;
        const short bv = f32_bf16((acc[m][n][r] + bj) * sc);
        if (three == 0)
          Qb[(size_t)(bh * 1024 + nn) * 64 + d] = bv;
        else if (three == 1)
          Kb[(size_t)(bh * 1024 + nn) * 64 + d] = bv;
        else
          Vt[(size_t)(bh * 64 + d) * 1024 + nn] = bv;
      }
    }
  }
}

// ----------------------------------------------------------- attention -----
// One block = 128 q-rows of one (b,h). 4 waves x 32 rows. KV tile = 64 keys.
// Swapped QK^T: S^T = mfma(A=K rows, B=Q rows) -> lane holds 16 keys of ONE
// query. Softmax reduce = 15 fmax + 2 shfl. P packed (cvt_pk) to per-wave LDS
// rows, read back as PV B-fragment. O^T accumulated, transposed via LDS at end.
__global__ __launch_bounds__(256, 2) void attn_kernel(
    const short* __restrict__ Qb, const short* __restrict__ Kb,
    const short* __restrict__ Vt, short* __restrict__ Ao) {
  __shared__ __align__(16) char smem[25600];
  short* Kf = (short*)smem;                 // 8 planes x 64 lanes x 8 bf16
  short* Vf = (short*)(smem + 8192);
  short* Pl = (short*)(smem + 16384);       // 4 waves x [16 q][72]

  const int tid = threadIdx.x, lane = tid & 63, w = tid >> 6;
  const int c = lane & 15, g = lane >> 4;
  const int bh = blockIdx.x >> 3, qb = blockIdx.x & 7;
  const int bb = bh >> 4, h = bh & 15;
  const int q0 = qb * 128 + w * 32;

  // Q fragments (B-operand: rows = queries)
  bf16x8 qf[2][2];
#pragma unroll
  for (int m = 0; m < 2; ++m)
#pragma unroll
    for (int ks = 0; ks < 2; ++ks)
      qf[m][ks] = *(const bf16x8*)(Qb + (size_t)(bh * 1024 + q0 + m * 16 + c) * 64 + ks * 32 + 8 * g);

  f32x4 o[2][4] = {};
  float mrun[2] = {-3.0e38f, -3.0e38f};
  float lrun[2] = {0.f, 0.f};

  // staging geometry (block-wide): row_r = K-key / V-d row, seg = 16B chunk
  const int row_r = tid >> 2, seg = tid & 3;
  const short* kp = Kb + (size_t)(bh * 1024 + row_r) * 64 + seg * 16;
  const short* vp = Vt + (size_t)(bh * 64 + row_r) * 1024 + seg * 16;
  short *kdst0, *kdst1, *vdst0, *vdst1;
  {
    const int d0a = seg * 16, d0b = seg * 16 + 8;
    const int pa = (row_r >> 4) * 2 + (d0a >> 5);
    const int pb = (row_r >> 4) * 2 + (d0b >> 5);
    const int sa = (row_r & 15) + 16 * ((d0a & 31) >> 3);
    const int sb = (row_r & 15) + 16 * ((d0b & 31) >> 3);
    kdst0 = &Kf[(pa * 64 + sa) * 8]; kdst1 = &Kf[(pb * 64 + sb) * 8];
    vdst0 = &Vf[(pa * 64 + sa) * 8]; vdst1 = &Vf[(pb * 64 + sb) * 8];
  }

  uint32_t* plw = (uint32_t*)(Pl + w * 1152);
  const short* plr = Pl + w * 1152;

  auto compute = [&]() {
#pragma unroll
    for (int m = 0; m < 2; ++m) {
      f32x4 s[4];
#pragma unroll
      for (int kt = 0; kt < 4; ++kt) {
        f32x4 sa = {};
#pragma unroll
        for (int ks = 0; ks < 2; ++ks) {
          bf16x8 kb = *(const bf16x8*)&Kf[((kt * 2 + ks) * 64 + lane) * 8];
          sa = __builtin_amdgcn_mfma_f32_16x16x32_bf16(kb, qf[m][ks], sa, 0, 0, 0);
        }
        s[kt] = sa;
      }
      // row max: 15 local fmax + 2 shfl (lanes sharing c)
      float vmax = s[0][0];
#pragma unroll
      for (int kt = 0; kt < 4; ++kt)
#pragma unroll
        for (int r = 0; r < 4; ++r) vmax = fmaxf(vmax, s[kt][r]);
      vmax = fmaxf(vmax, __shfl_xor(vmax, 16));
      vmax = fmaxf(vmax, __shfl_xor(vmax, 32));
      // defer-max: only rescale when some query's max grew by >8 (in log2 units)
      if (!__all(vmax <= mrun[m] + 8.0f)) {
        float mnew = fmaxf(mrun[m], vmax);
        float al = exp2_fast(mrun[m] - mnew);
        lrun[m] *= al;
#pragma unroll
        for (int dt = 0; dt < 4; ++dt) o[m][dt] *= al;
        mrun[m] = mnew;
      }
      float rs = 0.f;
#pragma unroll
      for (int kt = 0; kt < 4; ++kt) {
        float p0 = exp2_fast(s[kt][0] - mrun[m]);
        float p1 = exp2_fast(s[kt][1] - mrun[m]);
        float p2 = exp2_fast(s[kt][2] - mrun[m]);
        float p3 = exp2_fast(s[kt][3] - mrun[m]);
        rs += (p0 + p1) + (p2 + p3);
        u32x2 pk;
        pk[0] = cvt_pk_bf16(p0, p1);
        pk[1] = cvt_pk_bf16(p2, p3);
        *(u32x2*)&plw[c * 36 + kt * 8 + 2 * g] = pk;
      }
      rs += __shfl_xor(rs, 16);
      rs += __shfl_xor(rs, 32);
      lrun[m] += rs;
      // PV: O^T[d][q] += V^T x P^T
#pragma unroll
      for (int kk = 0; kk < 2; ++kk) {
        bf16x8 pb = *(const bf16x8*)(plr + c * 72 + kk * 32 + 8 * g);
#pragma unroll
        for (int dt = 0; dt < 4; ++dt) {
          bf16x8 vb = *(const bf16x8*)&Vf[((dt * 2 + kk) * 64 + lane) * 8];
          o[m][dt] = __builtin_amdgcn_mfma_f32_16x16x32_bf16(vb, pb, o[m][dt], 0, 0, 0);
        }
      }
    }
  };

  // T14 pipeline: issue tile t+1 global loads before compute(t); ds_write after.
  bf16x8 ka0, ka1, va0, va1, kc0, kc1, vc0, vc1;
  ka0 = *(const bf16x8*)(kp);     ka1 = *(const bf16x8*)(kp + 8);
  va0 = *(const bf16x8*)(vp);     va1 = *(const bf16x8*)(vp + 8);

  for (int t = 0; t < 16; t += 2) {
    __syncthreads();
    *(bf16x8*)kdst0 = ka0; *(bf16x8*)kdst1 = ka1;
    *(bf16x8*)vdst0 = va0; *(bf16x8*)vdst1 = va1;
    {
      const short* kpt = kp + (size_t)(t + 1) * 4096;
      const short* vpt = vp + (t + 1) * 64;
      kc0 = *(const bf16x8*)(kpt); kc1 = *(const bf16x8*)(kpt + 8);
      vc0 = *(const bf16x8*)(vpt); vc1 = *(const bf16x8*)(vpt + 8);
    }
    __syncthreads();
    compute();
    __syncthreads();
    *(bf16x8*)kdst0 = kc0; *(bf16x8*)kdst1 = kc1;
    *(bf16x8*)vdst0 = vc0; *(bf16x8*)vdst1 = vc1;
    if (t + 2 < 16) {
      const short* kpt = kp + (size_t)(t + 2) * 4096;
      const short* vpt = vp + (t + 2) * 64;
      ka0 = *(const bf16x8*)(kpt); ka1 = *(const bf16x8*)(kpt + 8);
      va0 = *(const bf16x8*)(vpt); va1 = *(const bf16x8*)(vpt + 8);
    }
    __syncthreads();
    compute();
  }

  // epilogue: transpose O^T -> O via LDS (reuse smem), coalesced bf16 stores
  __syncthreads();
  float* Osc = (float*)smem + w * (16 * 68);   // per-wave [16 q][68] f32
  const int qrow = lane >> 2, dseg = (lane & 3) << 4;
#pragma unroll
  for (int m = 0; m < 2; ++m) {
    const float inv = 1.0f / lrun[m];
#pragma unroll
    for (int dt = 0; dt < 4; ++dt)
#pragma unroll
      for (int r = 0; r < 4; ++r)
        Osc[c * 68 + dt * 16 + 4 * g + r] = o[m][dt][r] * inv;
    // wave-private region: compiler-inserted lgkm waits order write->read
#pragma unroll
    for (int j = 0; j < 2; ++j) {
      f32x4 a0 = *(f32x4*)&Osc[qrow * 68 + dseg + j * 8];
      f32x4 a1 = *(f32x4*)&Osc[qrow * 68 + dseg + j * 8 + 4];
      bf16x8 ob;
      ob[0] = f32_bf16(a0[0]); ob[1] = f32_bf16(a0[1]);
      ob[2] = f32_bf16(a0[2]); ob[3] = f32_bf16(a0[3]);
      ob[4] = f32_bf16(a1[0]); ob[5] = f32_bf16(a1[1]);
      ob[6] = f32_bf16(a1[2]); ob[7] = f32_bf16(a1[3]);
      *(bf16x8*)(Ao + (size_t)(bb * 1024 + q0 + m * 16 + qrow) * 1024 + h * 64 + dseg + j * 8) = ob;
    }
    __syncthreads();  // Osc reused by next m across waves? (per-wave, but keep waves in step)
  }
}

// --------------------------------------------------------------- GEMM2 -----
__global__ __launch_bounds__(256, 2) void gemm_proj_kernel(
    const short* __restrict__ A, const short* __restrict__ Bt,
    const float* __restrict__ bias, float* __restrict__ out) {
  __shared__ short Asm[128 * 64];
  __shared__ short Bsm[128 * 64];
  const int tid = threadIdx.x;
  const int lane = tid & 63;
  const int w = tid >> 6;
  const int wr = w >> 1, wc = w & 1;
  const int c = lane & 15, g = lane >> 4;

  const int NT = 8;  // 1024/128
  const int tm = blockIdx.x / NT, tn = blockIdx.x % NT;
  const int m0 = tm * 128, n0 = tn * 128;

  f32x4 acc[4][4] = {};

  for (int k0 = 0; k0 < 1024; k0 += 64) {
#pragma unroll
    for (int i = 0; i < 4; ++i) {
      int ch = (w * 4 + i) * 64 + lane;
      int r = ch >> 3, c8 = ch & 7;
      gload_lds16(A + (size_t)(m0 + r) * 1024 + k0 + c8 * 8, &Asm[ch * 8]);
      gload_lds16(Bt + (size_t)(n0 + r) * 1024 + k0 + c8 * 8, &Bsm[ch * 8]);
    }
    asm volatile("s_waitcnt vmcnt(0)" ::: "memory");
    __syncthreads();
#pragma unroll
    for (int kk = 0; kk < 2; ++kk) {
      bf16x8 a[4], b[4];
#pragma unroll
      for (int m = 0; m < 4; ++m)
        a[m] = *(const bf16x8*)&Asm[(wr * 64 + m * 16 + c) * 64 + kk * 32 + 8 * g];
#pragma unroll
      for (int n = 0; n < 4; ++n)
        b[n] = *(const bf16x8*)&Bsm[(wc * 64 + n * 16 + c) * 64 + kk * 32 + 8 * g];
#pragma unroll
      for (int m = 0; m < 4; ++m)
#pragma unroll
        for (int n = 0; n < 4; ++n)
          acc[m][n] = __builtin_amdgcn_mfma_f32_16x16x32_bf16(a[m], b[n], acc[m][n], 0, 0, 0);
    }
    __syncthreads();
  }

#pragma unroll
  for (int m = 0; m < 4; ++m) {
    const int i_base = m0 + wr * 64 + m * 16 + 4 * g;
#pragma unroll
    for (int n = 0; n < 4; ++n) {
      const int j = n0 + wc * 64 + n * 16 + c;
      const float bj = bias[j];
#pragma unroll
      for (int r = 0; r < 4; ++r)
        out[(size_t)(i_base + r) * 1024 + j] = acc[m][n][r] + bj;
    }
  }
}

// ------------------------------------------------------------- launch ------
extern "C" void kernel_launch(void* const* d_in, const int* in_sizes, int n_in,
                              void* d_out, int out_size, void* d_ws, size_t ws_size,
                              hipStream_t stream) {
  const float* x = (const float*)d_in[0];
  const float* w_qkv = (const float*)d_in[1];
  const float* b_qkv = (const float*)d_in[2];
  const float* w_proj = (const float*)d_in[3];
  const float* b_proj = (const float*)d_in[4];
  float* out = (float*)d_out;

  char* ws = (char*)d_ws;
  const size_t XB_OFF = 0;                       // 16 MB (reused as attn_out)
  const size_t WQKVT_OFF = 16777216;             // 6 MB
  const size_t WPROJT_OFF = WQKVT_OFF + 6291456; // 2 MB
  const size_t Q_OFF = WPROJT_OFF + 2097152;     // 16 MB
  const size_t K_OFF = Q_OFF + 16777216;         // 16 MB
  const size_t VT_OFF = K_OFF + 16777216;        // 16 MB
  short* xb = (short*)(ws + XB_OFF);
  short* wqkvT = (short*)(ws + WQKVT_OFF);
  short* wprojT = (short*)(ws + WPROJT_OFF);
  short* Qb = (short*)(ws + Q_OFF);
  short* Kb = (short*)(ws + K_OFF);
  short* Vt = (short*)(ws + VT_OFF);
  short* attn_o = xb;  // xb dead after GEMM1

  convert_x_kernel<<<dim3(4096), dim3(256), 0, stream>>>(x, xb);
  transpose_w_kernel<<<dim3(48, 16), dim3(256), 0, stream>>>(w_qkv, wqkvT, 3072);
  transpose_w_kernel<<<dim3(16, 16), dim3(256), 0, stream>>>(w_proj, wprojT, 1024);
  gemm_qkv_kernel<<<dim3(64 * 24), dim3(256), 0, stream>>>(xb, wqkvT, b_qkv, Qb, Kb, Vt);
  attn_kernel<<<dim3(1024), dim3(256), 0, stream>>>(Qb, Kb, Vt, attn_o);
  gemm_proj_kernel<<<dim3(64 * 8), dim3(256), 0, stream>>>(attn_o, wprojT, b_proj, out);
}